// Round 10
// baseline (90.882 us; speedup 1.0000x reference)
//
#include <hip/hip_runtime.h>

// VectorQuantiser on MI355X — round 10: persistent-A col-loop gemm.
// Round-9 lesson: __syncthreads() drains vmcnt(0) -> explicit prefetch useless;
// TLP + making staged loads L2-resident is what reduces barrier cost.
// gemm: one block = 64 rows x FULL K (A staged once, 32KB), loop over 8 col-tiles
// with double-buffered B (cbb = 512KB -> L2-resident -> cheap drains).
//
//   1 prep:     z_e -> bf16 zb (z_q slot bytes [0,16.8M)); cb -> bf16 cbb (ws);
//               rsqz / nse / rsqe.
//   2 gemm:     per col-iter epilogue: sim + top-2 per-64-strip cand encs
//               (z_q slot bytes [16.8M,20.8M)).
//   3 select1:  cand -> ids + loss partials (exact fp32 rescore of near-ties).
//   4 zq_gather: ids -> z_q.
//   5 finalize: tree-sum partials; loss = 1.25 * mean.

#define M_ROWS 32768
#define KCODES 1024
#define DDIM   256
#define ENC_BIG 33554432.0f

typedef __bf16 bf16_t;
typedef __attribute__((ext_vector_type(8))) bf16_t bf16x8;
typedef __attribute__((ext_vector_type(4))) float f32x4;

__device__ __forceinline__ unsigned short f2bf(float f) {
  unsigned u = __float_as_uint(f);
  u += 0x7FFFu + ((u >> 16) & 1u);   // round-to-nearest-even
  return (unsigned short)(u >> 16);
}

__device__ __forceinline__ float wave_sum(float p) {
#pragma unroll
  for (int o = 1; o < 64; o <<= 1) p += __shfl_xor(p, o);
  return p;
}
__device__ __forceinline__ float wave_min(float p) {
#pragma unroll
  for (int o = 1; o < 64; o <<= 1) p = fminf(p, __shfl_xor(p, o));
  return p;
}

// ---------------- Kernel 1: convert + norms ----------------
__global__ __launch_bounds__(256) void prep_kernel(
    const float* __restrict__ ze, const float* __restrict__ cb,
    unsigned short* __restrict__ zb, unsigned short* __restrict__ cbb,
    float* __restrict__ rsqz,
    float* __restrict__ nse, float* __restrict__ rsqe)
{
  const int t = threadIdx.x;
  const int lane = t & 63;
  const int row = blockIdx.x * 4 + (t >> 6);         // wave per row; rows 0..33791
  if (row < M_ROWS) {
    const float4 z = ((const float4*)ze)[(size_t)row * 64 + lane];
    ushort4 u;
    u.x = f2bf(z.x); u.y = f2bf(z.y); u.z = f2bf(z.z); u.w = f2bf(z.w);
    ((ushort4*)zb)[(size_t)row * 64 + lane] = u;
    float p = wave_sum(z.x*z.x + z.y*z.y + z.z*z.z + z.w*z.w);
    if (lane == 0) rsqz[row] = 1.0f / sqrtf(p);
  } else {
    const int r = row - M_ROWS;                      // 0..1023
    const float4 e = ((const float4*)cb)[(size_t)r * 64 + lane];
    ushort4 u;
    u.x = f2bf(e.x); u.y = f2bf(e.y); u.z = f2bf(e.z); u.w = f2bf(e.w);
    ((ushort4*)cbb)[(size_t)r * 64 + lane] = u;
    float p = wave_sum(e.x*e.x + e.y*e.y + e.z*e.z + e.w*e.w);
    if (lane == 0) { nse[r] = p; rsqe[r] = 1.0f / sqrtf(p); }
  }
}

// ---------------- Kernel 2: persistent-A col-loop GEMM + sim + cand ----------------
__global__ __launch_bounds__(256, 2) void gemm_kernel(
    const unsigned short* __restrict__ zb, const unsigned short* __restrict__ cbb,
    const float* __restrict__ rsqz, const float* __restrict__ rsqe_g,
    const float* __restrict__ nse_g,
    float* __restrict__ sim, float* __restrict__ cand)
{
  __shared__ __attribute__((aligned(128))) unsigned short A[64 * 256];     // 32 KB, full K
  __shared__ __attribute__((aligned(128))) unsigned short Bt[2][128 * 64]; // 2 x 16 KB

  const int t = threadIdx.x;
  const int wv = t >> 6, lane = t & 63;
  const long row0 = (long)blockIdx.x * 64;           // 512 blocks = 2/CU, all resident

  const int r16 = lane & 15, g = lane >> 4;
  const int wm = wv >> 1, wn = wv & 1;

  // ---- A: stage 64 rows x 256 K once. Linear LDS dest (global_load_lds),
  //      pre-swizzled source: phys quad p holds logical q=(p&24)|((p^(r&7))&7).
  {
    const int p = lane & 31;
#pragma unroll
    for (int i = 0; i < 8; ++i) {
      const int r = i * 8 + wv * 2 + (lane >> 5);
      const int q = (p & 24) | ((p ^ (r & 7)) & 7);
      const unsigned short* src = zb + (size_t)(row0 + r) * DDIM + q * 8;
      __builtin_amdgcn_global_load_lds(
          (const __attribute__((address_space(1))) void*)src,
          (__attribute__((address_space(3))) void*)&A[(i * 8 + wv * 2) * 256],
          16, 0, 0);
    }
  }

  // ---- B stage: col-tile c, K-step kt -> buffer buf (validated round-7 path) ----
  const int rr = lane >> 3, qq = lane & 7;
  const int sq = ((qq ^ rr) << 3);                   // pre-swizzled source quad (16B)
  auto stageB = [&](int buf, int c, int kt) {
    const int k0 = kt * 64;
#pragma unroll
    for (int i = 0; i < 4; ++i) {
      const int rbase = wv * 32 + i * 8;
      const unsigned short* src = cbb + ((size_t)(c * 128 + rbase + rr)) * DDIM + k0 + sq;
      __builtin_amdgcn_global_load_lds(
          (const __attribute__((address_space(1))) void*)src,
          (__attribute__((address_space(3))) void*)&Bt[buf][rbase * 64],
          16, 0, 0);
    }
  };

  stageB(0, 0, 0);
  __syncthreads();                                   // A + B(0,0) ready

  f32x4 acc[2][4] = {};

  for (int u = 0; u < 32; ++u) {                     // u = c*4 + kt
    const int kt = u & 3;
    if (u < 31) stageB((u + 1) & 1, (u + 1) >> 2, (u + 1) & 3);  // issue next EARLY
    const unsigned short* Bcur = Bt[u & 1];

#pragma unroll
    for (int ks = 0; ks < 2; ++ks) {
      const int q = kt * 8 + ks * 4 + g;             // logical A quad 0..31
      bf16x8 af[2], bfr[4];
#pragma unroll
      for (int mi = 0; mi < 2; ++mi) {
        const int r  = wm * 32 + mi * 16 + r16;
        const int ph = (q & 24) | ((q ^ (r & 7)) & 7);
        af[mi] = *(const bf16x8*)((const char*)A + r * 512 + ph * 16);
      }
#pragma unroll
      for (int ni = 0; ni < 4; ++ni) {
        const int r  = wn * 64 + ni * 16 + r16;
        const int ph = (ks * 4 + g) ^ (r & 7);
        bfr[ni] = *(const bf16x8*)((const char*)Bcur + r * 128 + ph * 16);
      }
#pragma unroll
      for (int mi = 0; mi < 2; ++mi)
#pragma unroll
        for (int ni = 0; ni < 4; ++ni)
          acc[mi][ni] = __builtin_amdgcn_mfma_f32_16x16x32_bf16(af[mi], bfr[ni], acc[mi][ni], 0, 0, 0);
    }
    __syncthreads();   // drains next-B DMA (L2-resident ~200cy) + protects buffer

    if (kt == 3) {
      // ---- per-col epilogue (round-5-validated): sim + top-2 cand ----
      const int c = u >> 2;
      const int col0 = c * 128;
      const int strip = c * 2 + wn;                  // 0..15
#pragma unroll
      for (int mi = 0; mi < 2; ++mi) {
#pragma unroll
        for (int j = 0; j < 4; ++j) {
          const int rloc = wm * 32 + mi * 16 + g * 4 + j;
          const long row = row0 + rloc;
          const float rz = rsqz[row];
          float* so = sim + (size_t)row * KCODES + col0 + wn * 64 + r16;
          float e1 = ENC_BIG, e2 = ENC_BIG;
#pragma unroll
          for (int ni = 0; ni < 4; ++ni) {
            const int colk = col0 + wn * 64 + ni * 16 + r16;
            const float d = acc[mi][ni][j];
            so[ni * 16] = d * rz * rsqe_g[colk];
            const float v = nse_g[colk] - 2.0f * d;
            const float enc = floorf((v + 1024.0f) * 8.0f) * 1024.0f + (float)colk;
            if (enc < e1) { e2 = e1; e1 = enc; } else e2 = fminf(e2, enc);
          }
#pragma unroll
          for (int m = 1; m < 16; m <<= 1) {         // top-2 across 16-lane group
            const float p1 = __shfl_xor(e1, m);
            const float p2 = __shfl_xor(e2, m);
            const float n1 = fminf(e1, p1);
            const float n2 = fminf(fmaxf(e1, p1), fminf(e2, p2));
            e1 = n1; e2 = n2;
          }
          if (r16 == 0)
            ((float2*)cand)[row * 16 + strip] = make_float2(e1, e2);
        }
      }
      // reset accumulators AFTER all components read (round-4 lesson)
#pragma unroll
      for (int mi = 0; mi < 2; ++mi)
#pragma unroll
        for (int ni = 0; ni < 4; ++ni)
          acc[mi][ni] = (f32x4)(0.0f);
    }
  }
}

// ---------------- Kernel 3: candidate argmin -> ids + loss partials ----------------
__global__ __launch_bounds__(256) void select1_kernel(
    const float* __restrict__ ze, const float* __restrict__ cb,
    const float* __restrict__ cand, const float* __restrict__ nse,
    const float* __restrict__ rsqz,
    float* __restrict__ ids, float* __restrict__ partials)
{
  __shared__ float s_part[4];
  const int t = threadIdx.x;
  const int lane = t & 63;
  const int row  = blockIdx.x * 4 + (t >> 6);        // wave per row

  const float e = (lane < 32) ? cand[(size_t)row * 32 + lane] : ENC_BIG;
  const float m_enc = wave_min(e);
  const float qmin  = floorf(m_enc * 0.0009765625f); // exact /1024
  const float ql    = floorf(e * 0.0009765625f);
  unsigned long long msk = __ballot(ql <= qmin + 16.0f);  // margin 2.0 dist units
  int kbest;
  float dmin;                                        // dist - nsz for the winner
  if (__popcll(msk) == 1) {
    kbest = ((int)m_enc) & 1023;
    dmin  = qmin * 0.125f - 1024.0f;                 // decode quantized v
  } else {
    const float4 zr = ((const float4*)ze)[(size_t)row * 64 + lane];
    float tbest = INFINITY; kbest = KCODES;
    while (msk) {                                    // wave-uniform
      const int lb = __ffsll(msk) - 1;
      msk &= msk - 1;
      const int kc = ((int)__shfl(e, lb)) & 1023;
      const float4 er = ((const float4*)cb)[(size_t)kc * 64 + lane];
      const float p = wave_sum(zr.x*er.x + zr.y*er.y + zr.z*er.z + zr.w*er.w);
      const float tv = nse[kc] - 2.0f * p;           // exact fp32 dist - nsz
      if (tv < tbest || (tv == tbest && kc < kbest)) { tbest = tv; kbest = kc; }
    }
    dmin = tbest;
  }
  if (lane == 0) {
    const float rz = rsqz[row];
    const float nsz = 1.0f / (rz * rz);
    ids[row] = (float)kbest;
    s_part[t >> 6] = sqrtf(fmaxf(nsz + dmin, 0.0f));
  }
  __syncthreads();
  if (t == 0)
    partials[blockIdx.x] = (s_part[0] + s_part[1]) + (s_part[2] + s_part[3]);
}

// ---------------- Kernel 4: z_q gather ----------------
__global__ __launch_bounds__(256) void zq_gather_kernel(
    const float* __restrict__ cb, const float* __restrict__ ids,
    float* __restrict__ zq)
{
  const int t = threadIdx.x;
  const int wv = t >> 6, lane = t & 63;
  const int row = blockIdx.x * 4 + wv;
  const int kbest = (int)ids[row];
  ((float4*)zq)[(size_t)row * 64 + lane] = ((const float4*)cb)[(size_t)kbest * 64 + lane];
}

// ---------------- Kernel 5: finalize loss (deterministic tree sum) ----------------
__global__ __launch_bounds__(256) void finalize_kernel(
    const float* __restrict__ partials, float* __restrict__ out_loss)
{
  __shared__ float s[4];
  const int t = threadIdx.x;
  float p = 0.0f;
#pragma unroll
  for (int i = 0; i < 32; ++i) p += partials[t + i * 256];  // 8192, fixed order
  p = wave_sum(p);
  if ((t & 63) == 0) s[t >> 6] = p;
  __syncthreads();
  if (t == 0) out_loss[0] = 1.25f * ((s[0] + s[1]) + (s[2] + s[3])) / 32768.0f;
}

extern "C" void kernel_launch(void* const* d_in, const int* in_sizes, int n_in,
                              void* d_out, int out_size, void* d_ws, size_t ws_size,
                              hipStream_t stream) {
  const float* ze = (const float*)d_in[0];
  const float* cb = (const float*)d_in[1];

  float* out  = (float*)d_out;
  float* zq   = out;                    // 8388608
  float* sim  = out + 8388608;          // 33554432
  float* ids  = out + 41943040;         // 32768
  float* lout = out + 41975808;         // 1

  // Parked in the z_q output slot (dead until zq_gather):
  //   zb   = bf16 z_e, bytes [0, 16.8M)
  //   cand = 4 MB candidate encs, bytes [16.8M, 20.8M)
  unsigned short* zb = (unsigned short*)d_out;
  float* cand = (float*)((char*)d_out + 16777216);

  // ws layout (~700 KB, under the empirically-confirmed ~800 KB floor)
  char* w = (char*)d_ws;
  unsigned short* cbb = (unsigned short*)w;      // 512 KB
  float* rsqz     = (float*)(w + 524288);        // 128 KB
  float* nse      = (float*)(w + 655360);        // 4 KB
  float* rsqe     = (float*)(w + 659456);        // 4 KB
  float* partials = (float*)(w + 663552);        // 32 KB (8192 f32)

  prep_kernel<<<8448, 256, 0, stream>>>(ze, cb, zb, cbb, rsqz, nse, rsqe);
  gemm_kernel<<<512, 256, 0, stream>>>(zb, cbb, rsqz, rsqe, nse, sim, cand);
  select1_kernel<<<8192, 256, 0, stream>>>(ze, cb, cand, nse, rsqz, ids, partials);
  zq_gather_kernel<<<8192, 256, 0, stream>>>(cb, ids, zq);
  finalize_kernel<<<1, 256, 0, stream>>>(partials, lout);
}

// Round 11
// 80.627 us; speedup vs baseline: 1.1272x; 1.1272x over previous
//
#include <hip/hip_runtime.h>

// VectorQuantiser on MI355X — round 11: occupancy-doubled gemm.
// R8 counters: gemm 60us/rep, MfmaUtil 12%, VALUBusy 26%, HBM 42%, occupancy
// 22.9% == 2 blocks/CU (128 VGPR + 64 AGPR acc = ~192 unified regs -> 2 waves/SIMD).
// Fix: 8 waves/block (512 thr), wave-tile 64x32 -> acc 32 AGPR, ~<=128 regs
// -> 4 waves/SIMD -> ~50% occupancy. Same LDS/staging/barriers/traffic as R7.
// Cand granularity: top-2 per 32-col strip (64 encs/row, 8 MB, in z_q slot).
//
//   1 prep:      z_e -> bf16 zb (z_q slot [0,16.8M)); cb -> bf16 cbb (ws); norms.
//   2 gemm:      128x128 tile bf16 MFMA via global_load_lds; epilogue: sim +
//                top-2 per-32-strip cand encs (z_q slot [16.8M,24.8M)).
//   3 select1:   cand (64 encs/row) -> ids + loss partials (fp32 rescore of ties).
//   4 zq_gather: ids -> z_q.
//   5 finalize:  tree-sum partials; loss = 1.25 * mean.

#define M_ROWS 32768
#define KCODES 1024
#define DDIM   256
#define ENC_BIG 33554432.0f

typedef __bf16 bf16_t;
typedef __attribute__((ext_vector_type(8))) bf16_t bf16x8;
typedef __attribute__((ext_vector_type(4))) float f32x4;

__device__ __forceinline__ unsigned short f2bf(float f) {
  unsigned u = __float_as_uint(f);
  u += 0x7FFFu + ((u >> 16) & 1u);   // round-to-nearest-even
  return (unsigned short)(u >> 16);
}

__device__ __forceinline__ float wave_sum(float p) {
#pragma unroll
  for (int o = 1; o < 64; o <<= 1) p += __shfl_xor(p, o);
  return p;
}
__device__ __forceinline__ float wave_min(float p) {
#pragma unroll
  for (int o = 1; o < 64; o <<= 1) p = fminf(p, __shfl_xor(p, o));
  return p;
}

// ---------------- Kernel 1: convert + norms ----------------
__global__ __launch_bounds__(256) void prep_kernel(
    const float* __restrict__ ze, const float* __restrict__ cb,
    unsigned short* __restrict__ zb, unsigned short* __restrict__ cbb,
    float* __restrict__ rsqz,
    float* __restrict__ nse, float* __restrict__ rsqe)
{
  const int t = threadIdx.x;
  const int lane = t & 63;
  const int row = blockIdx.x * 4 + (t >> 6);         // wave per row; rows 0..33791
  if (row < M_ROWS) {
    const float4 z = ((const float4*)ze)[(size_t)row * 64 + lane];
    ushort4 u;
    u.x = f2bf(z.x); u.y = f2bf(z.y); u.z = f2bf(z.z); u.w = f2bf(z.w);
    ((ushort4*)zb)[(size_t)row * 64 + lane] = u;
    float p = wave_sum(z.x*z.x + z.y*z.y + z.z*z.z + z.w*z.w);
    if (lane == 0) rsqz[row] = 1.0f / sqrtf(p);
  } else {
    const int r = row - M_ROWS;                      // 0..1023
    const float4 e = ((const float4*)cb)[(size_t)r * 64 + lane];
    ushort4 u;
    u.x = f2bf(e.x); u.y = f2bf(e.y); u.z = f2bf(e.z); u.w = f2bf(e.w);
    ((ushort4*)cbb)[(size_t)r * 64 + lane] = u;
    float p = wave_sum(e.x*e.x + e.y*e.y + e.z*e.z + e.w*e.w);
    if (lane == 0) { nse[r] = p; rsqe[r] = 1.0f / sqrtf(p); }
  }
}

// ---------------- Kernel 2: GEMM (8-wave, low-reg) + sim + cand epilogue ----------------
__global__ __launch_bounds__(512, 4) void gemm_kernel(
    const unsigned short* __restrict__ zb, const unsigned short* __restrict__ cbb,
    const float* __restrict__ rsqz, const float* __restrict__ rsqe_g,
    const float* __restrict__ nse_g,
    float* __restrict__ sim, float* __restrict__ cand)
{
  __shared__ __attribute__((aligned(128))) unsigned short lds[16384]; // A [0,8192), B [8192,16384)
  const int t    = threadIdx.x;
  const int wv   = t >> 6, lane = t & 63;
  const int bid  = blockIdx.x;
  const int swz  = (bid & 7) * 256 + (bid >> 3);     // XCD swizzle, nwg=2048 % 8 == 0
  const long row0 = (long)(swz >> 3) * 128;          // 256 row tiles
  const int  col0 = (swz & 7) * 128;                 // 8 col tiles

  f32x4 acc[4][2] = {};                              // 64(M) x 32(N) per wave = 32 AGPR

  const int rr = lane >> 3, qq = lane & 7;
  const int sq = ((qq ^ rr) << 3);                   // pre-swizzled source quad (16B)
  const int r16 = lane & 15, g = lane >> 4;
  const int wm2 = wv >> 2, wn2 = wv & 3;             // 2(M) x 4(N) wave grid

  for (int kt = 0; kt < 4; ++kt) {
    const int k0 = kt * 64;
#pragma unroll
    for (int i = 0; i < 2; ++i) {                    // 8 waves x 2 = rows 0..127 in 8s
      const int rbase = wv * 16 + i * 8;
      const unsigned short* srca = zb  + ((size_t)(row0 + rbase + rr)) * DDIM + k0 + sq;
      const unsigned short* srcb = cbb + ((size_t)(col0 + rbase + rr)) * DDIM + k0 + sq;
      __builtin_amdgcn_global_load_lds((const __attribute__((address_space(1))) void*)srca,
                                       (__attribute__((address_space(3))) void*)&lds[rbase * 64],
                                       16, 0, 0);
      __builtin_amdgcn_global_load_lds((const __attribute__((address_space(1))) void*)srcb,
                                       (__attribute__((address_space(3))) void*)&lds[8192 + rbase * 64],
                                       16, 0, 0);
    }
    __syncthreads();
#pragma unroll
    for (int ks = 0; ks < 2; ++ks) {
      bf16x8 af[4], bfr[2];
#pragma unroll
      for (int mi = 0; mi < 4; ++mi) {
        const int r  = wm2 * 64 + mi * 16 + r16;
        const int qy = ((ks * 4 + g) ^ (r & 7)) << 4;
        af[mi] = *(const bf16x8*)((const char*)lds + r * 128 + qy);
      }
#pragma unroll
      for (int ni = 0; ni < 2; ++ni) {
        const int r  = wn2 * 32 + ni * 16 + r16;
        const int qy = ((ks * 4 + g) ^ (r & 7)) << 4;
        bfr[ni] = *(const bf16x8*)((const char*)lds + 16384 + r * 128 + qy);
      }
#pragma unroll
      for (int mi = 0; mi < 4; ++mi)
#pragma unroll
        for (int ni = 0; ni < 2; ++ni)
          acc[mi][ni] = __builtin_amdgcn_mfma_f32_16x16x32_bf16(af[mi], bfr[ni], acc[mi][ni], 0, 0, 0);
    }
    __syncthreads();
  }

  // Epilogue: sim write + top-2 per 32-col strip candidates.
  // C/D layout: col = lane&15, row = (lane>>4)*4 + j.
  const int strip = ((col0 >> 5) | wn2);             // global 32-col strip 0..31
#pragma unroll
  for (int mi = 0; mi < 4; ++mi) {
#pragma unroll
    for (int j = 0; j < 4; ++j) {
      const long row = row0 + wm2 * 64 + mi * 16 + g * 4 + j;
      const float rz = rsqz[row];
      float* so = sim + (size_t)row * KCODES + col0 + wn2 * 32 + r16;
      float e1 = ENC_BIG, e2 = ENC_BIG;
#pragma unroll
      for (int ni = 0; ni < 2; ++ni) {
        const int colk = col0 + wn2 * 32 + ni * 16 + r16;
        const float d = acc[mi][ni][j];
        so[ni * 16] = d * rz * rsqe_g[colk];
        const float v = nse_g[colk] - 2.0f * d;
        const float enc = floorf((v + 1024.0f) * 8.0f) * 1024.0f + (float)colk;
        if (enc < e1) { e2 = e1; e1 = enc; } else e2 = fminf(e2, enc);
      }
#pragma unroll
      for (int m = 1; m < 16; m <<= 1) {             // top-2 across the 16-lane group
        const float p1 = __shfl_xor(e1, m);
        const float p2 = __shfl_xor(e2, m);
        const float n1 = fminf(e1, p1);
        const float n2 = fminf(fmaxf(e1, p1), fminf(e2, p2));
        e1 = n1; e2 = n2;
      }
      if (r16 == 0)
        ((float2*)cand)[row * 32 + strip] = make_float2(e1, e2);
    }
  }
}

// ---------------- Kernel 3: candidate argmin -> ids + loss partials ----------------
__global__ __launch_bounds__(256) void select1_kernel(
    const float* __restrict__ ze, const float* __restrict__ cb,
    const float* __restrict__ cand, const float* __restrict__ nse,
    const float* __restrict__ rsqz,
    float* __restrict__ ids, float* __restrict__ partials)
{
  __shared__ float s_part[4];
  const int t = threadIdx.x;
  const int lane = t & 63;
  const int row  = blockIdx.x * 4 + (t >> 6);        // wave per row

  const float e = cand[(size_t)row * 64 + lane];     // 32 strips x 2 = 64 encs
  const float m_enc = wave_min(e);
  const float qmin  = floorf(m_enc * 0.0009765625f); // exact /1024
  const float ql    = floorf(e * 0.0009765625f);
  unsigned long long msk = __ballot(ql <= qmin + 16.0f);  // margin 2.0 dist units
  int kbest;
  float dmin;                                        // dist - nsz for the winner
  if (__popcll(msk) == 1) {
    kbest = ((int)m_enc) & 1023;
    dmin  = qmin * 0.125f - 1024.0f;                 // decode quantized v
  } else {
    const float4 zr = ((const float4*)ze)[(size_t)row * 64 + lane];
    float tbest = INFINITY; kbest = KCODES;
    while (msk) {                                    // wave-uniform
      const int lb = __ffsll(msk) - 1;
      msk &= msk - 1;
      const int kc = ((int)__shfl(e, lb)) & 1023;
      const float4 er = ((const float4*)cb)[(size_t)kc * 64 + lane];
      const float p = wave_sum(zr.x*er.x + zr.y*er.y + zr.z*er.z + zr.w*er.w);
      const float tv = nse[kc] - 2.0f * p;           // exact fp32 dist - nsz
      if (tv < tbest || (tv == tbest && kc < kbest)) { tbest = tv; kbest = kc; }
    }
    dmin = tbest;
  }
  if (lane == 0) {
    const float rz = rsqz[row];
    const float nsz = 1.0f / (rz * rz);
    ids[row] = (float)kbest;
    s_part[t >> 6] = sqrtf(fmaxf(nsz + dmin, 0.0f));
  }
  __syncthreads();
  if (t == 0)
    partials[blockIdx.x] = (s_part[0] + s_part[1]) + (s_part[2] + s_part[3]);
}

// ---------------- Kernel 4: z_q gather ----------------
__global__ __launch_bounds__(256) void zq_gather_kernel(
    const float* __restrict__ cb, const float* __restrict__ ids,
    float* __restrict__ zq)
{
  const int t = threadIdx.x;
  const int wv = t >> 6, lane = t & 63;
  const int row = blockIdx.x * 4 + wv;
  const int kbest = (int)ids[row];
  ((float4*)zq)[(size_t)row * 64 + lane] = ((const float4*)cb)[(size_t)kbest * 64 + lane];
}

// ---------------- Kernel 5: finalize loss (deterministic tree sum) ----------------
__global__ __launch_bounds__(256) void finalize_kernel(
    const float* __restrict__ partials, float* __restrict__ out_loss)
{
  __shared__ float s[4];
  const int t = threadIdx.x;
  float p = 0.0f;
#pragma unroll
  for (int i = 0; i < 32; ++i) p += partials[t + i * 256];  // 8192, fixed order
  p = wave_sum(p);
  if ((t & 63) == 0) s[t >> 6] = p;
  __syncthreads();
  if (t == 0) out_loss[0] = 1.25f * ((s[0] + s[1]) + (s[2] + s[3])) / 32768.0f;
}

extern "C" void kernel_launch(void* const* d_in, const int* in_sizes, int n_in,
                              void* d_out, int out_size, void* d_ws, size_t ws_size,
                              hipStream_t stream) {
  const float* ze = (const float*)d_in[0];
  const float* cb = (const float*)d_in[1];

  float* out  = (float*)d_out;
  float* zq   = out;                    // 8388608
  float* sim  = out + 8388608;          // 33554432
  float* ids  = out + 41943040;         // 32768
  float* lout = out + 41975808;         // 1

  // Parked in the z_q output slot (dead until zq_gather):
  //   zb   = bf16 z_e, bytes [0, 16.8M)
  //   cand = 8 MB candidate encs (32 strips x float2 per row), [16.8M, 24.8M)
  unsigned short* zb = (unsigned short*)d_out;
  float* cand = (float*)((char*)d_out + 16777216);

  // ws layout (~700 KB, under the empirically-confirmed ~800 KB floor)
  char* w = (char*)d_ws;
  unsigned short* cbb = (unsigned short*)w;      // 512 KB
  float* rsqz     = (float*)(w + 524288);        // 128 KB
  float* nse      = (float*)(w + 655360);        // 4 KB
  float* rsqe     = (float*)(w + 659456);        // 4 KB
  float* partials = (float*)(w + 663552);        // 32 KB (8192 f32)

  prep_kernel<<<8448, 256, 0, stream>>>(ze, cb, zb, cbb, rsqz, nse, rsqe);
  gemm_kernel<<<2048, 512, 0, stream>>>(zb, cbb, rsqz, rsqe, nse, sim, cand);
  select1_kernel<<<8192, 256, 0, stream>>>(ze, cb, cand, nse, rsqz, ids, partials);
  zq_gather_kernel<<<8192, 256, 0, stream>>>(cb, ids, zq);
  finalize_kernel<<<1, 256, 0, stream>>>(partials, lout);
}